// Round 7
// baseline (440.183 us; speedup 1.0000x reference)
//
#include <hip/hip_runtime.h>

#define C 4096
#define NROWS 16384
#define NBLK 1024
#define TPB 512
#define RPB 16        // rows per block in phases 1/4
#define NCTR 8        // barrier sub-counters

typedef float f32x4 __attribute__((ext_vector_type(4)));

// Two-level grid barrier (1024 arrivals): blocks fetch_add(ACQ_REL) one of 8
// sub-counters (128 serialized RMWs/line, parallel across lines); block 0
// aggregates with RELAXED polls and publishes a RELEASE flag; everyone else
// RELAXED-polls the flag and does ONE ACQUIRE load after (single buffer_inv
// per block per barrier — R5's per-poll-inv bug stays fixed).
// Counters+flag memset to 0 each launch; rounds r = 1,2,3.
__device__ __forceinline__ void grid_barrier(unsigned* cnt, unsigned* flag,
                                             unsigned r, int bidx) {
    __syncthreads();
    if (threadIdx.x == 0) {
        __hip_atomic_fetch_add(&cnt[bidx & (NCTR - 1)], 1u, __ATOMIC_ACQ_REL,
                               __HIP_MEMORY_SCOPE_AGENT);
        if (bidx == 0) {
            for (int i = 0; i < NCTR; ++i) {
                while (__hip_atomic_load(&cnt[i], __ATOMIC_RELAXED,
                                         __HIP_MEMORY_SCOPE_AGENT) < r * (NBLK / NCTR)) {
                    __builtin_amdgcn_s_sleep(8);
                }
            }
            __hip_atomic_store(flag, r, __ATOMIC_RELEASE, __HIP_MEMORY_SCOPE_AGENT);
        } else {
            while (__hip_atomic_load(flag, __ATOMIC_RELAXED,
                                     __HIP_MEMORY_SCOPE_AGENT) < r) {
                __builtin_amdgcn_s_sleep(8);
            }
        }
        unsigned v = __hip_atomic_load(flag, __ATOMIC_ACQUIRE,
                                       __HIP_MEMORY_SCOPE_AGENT);
        asm volatile("" :: "v"(v));  // keep the acquire (and its inv) alive
    }
    __syncthreads();
}

__global__ __launch_bounds__(TPB, 8)  // 8-wave blocks, 8 waves/EU -> 4 blocks/CU, 32 waves/CU
void fused_kernel(const float* __restrict__ x, const float* __restrict__ W,
                  const float* __restrict__ b, const int* __restrict__ sf,
                  float* __restrict__ out, float* __restrict__ ws) {
    float* part = ws;                              // [NBLK][C] partials (16 MiB)
    float* gsum = ws + (size_t)NBLK * C;           // [C]
    unsigned* cnt = (unsigned*)(gsum + C + 64);    // 8 sub-counters (padded off gsum)
    unsigned* flag = cnt + NCTR;                   // release flag

    __shared__ float lds[TPB];
    __shared__ float red[8];

    const int t = threadIdx.x;                     // 0..511
    const int bidx = blockIdx.x;                   // 0..1023
    const int r0 = bidx * RPB;
    const float sf0 = (float)sf[0];

    // ---- Phase 1: column partials of my 16-row slice (2 f32x4 cols/thread) ----
    {
        const f32x4* xv = (const f32x4*)x + (size_t)r0 * (C / 4);
        f32x4 a0 = {0.f, 0.f, 0.f, 0.f}, a1 = {0.f, 0.f, 0.f, 0.f};
#pragma unroll 4
        for (int r = 0; r < RPB; ++r) {
            a0 += xv[(size_t)r * (C / 4) + t];
            a1 += xv[(size_t)r * (C / 4) + t + 512];
        }
        f32x4* pv = (f32x4*)part + (size_t)bidx * (C / 4);
        pv[t] = a0;
        pv[t + 512] = a1;
    }
    grid_barrier(cnt, flag, 1, bidx);

    // ---- Phase 2: fold part[1024][C] -> gsum (64 blocks, 64 cols each) ----
    if (bidx < 64) {
        const int col = (bidx << 6) + (t & 63);
        const int rg = t >> 6;                     // 0..7
        float s = 0.f;
#pragma unroll 8
        for (int k = 0; k < NBLK / 8; ++k)         // rows rg, rg+8, ...
            s += part[(size_t)(rg + (k << 3)) * C + col];
        lds[t] = s;
        __syncthreads();
        if (t < 64) {
            float tot = 0.f;
#pragma unroll
            for (int k = 0; k < 8; ++k) tot += lds[(k << 6) + t];
            gsum[(bidx << 6) + t] = tot;
        }
    }
    grid_barrier(cnt, flag, 2, bidx);

    // ---- Phase 3: 4 rows/block, 2 waves/row: s[row]=sigmoid(sf*(W@gsum/N+b)) ----
    {
        const int wave = t >> 6, lane = t & 63;
        const int row = (bidx << 2) + (wave >> 1);
        const int half = wave & 1;                 // which 512-f32x4 half of the row
        const f32x4* wv = (const f32x4*)(W + (size_t)row * C) + (half << 9);
        const f32x4* gv = (const f32x4*)gsum + (half << 9);
        float acc = 0.f;
#pragma unroll
        for (int i = 0; i < 8; ++i) {
            const f32x4 w4 = __builtin_nontemporal_load(wv + (i << 6) + lane);
            const f32x4 g4 = gv[(i << 6) + lane];
            acc += w4.x * g4.x + w4.y * g4.y + w4.z * g4.z + w4.w * g4.w;
        }
#pragma unroll
        for (int off = 32; off; off >>= 1) acc += __shfl_down(acc, off);
        if (lane == 0) red[wave] = acc;
        __syncthreads();
        if (t < 4) {
            const int row4 = (bidx << 2) + t;
            const float dot = red[t << 1] + red[(t << 1) | 1];
            const float y = dot * (1.0f / NROWS) + b[row4];
            out[(size_t)NROWS * C + row4] = 1.0f / (1.0f + __expf(-sf0 * y));
        }
    }
    grid_barrier(cnt, flag, 3, bidx);

    // ---- Phase 4: out = x * s over my same 16-row slice (L3-warm re-read) ----
    {
        const f32x4* sv = (const f32x4*)(out + (size_t)NROWS * C);
        const f32x4 sc0 = sv[t], sc1 = sv[t + 512];
        const f32x4* xv = (const f32x4*)x + (size_t)r0 * (C / 4);
        f32x4* ov = (f32x4*)out + (size_t)r0 * (C / 4);
#pragma unroll 4
        for (int r = 0; r < RPB; ++r) {
            f32x4 v0 = xv[(size_t)r * (C / 4) + t];
            f32x4 v1 = xv[(size_t)r * (C / 4) + t + 512];
            v0 *= sc0;
            v1 *= sc1;
            __builtin_nontemporal_store(v0, ov + (size_t)r * (C / 4) + t);
            __builtin_nontemporal_store(v1, ov + (size_t)r * (C / 4) + t + 512);
        }
    }
}

extern "C" void kernel_launch(void* const* d_in, const int* in_sizes, int n_in,
                              void* d_out, int out_size, void* d_ws, size_t ws_size,
                              hipStream_t stream) {
    const float* x = (const float*)d_in[0];   // [NROWS, C] fp32
    const float* W = (const float*)d_in[1];   // [C, C] fp32
    const float* b = (const float*)d_in[2];   // [C] fp32
    const int* sf  = (const int*)d_in[3];     // scalar int

    float* out = (float*)d_out;               // [NROWS*C] x_out ++ [C] x_scale
    float* ws  = (float*)d_ws;

    // Zero the barrier sub-counters + flag (36 B) each launch.
    const size_t bar_off = ((size_t)NBLK * C + C + 64) * sizeof(float);
    hipMemsetAsync((char*)d_ws + bar_off, 0, (NCTR + 1) * sizeof(unsigned), stream);

    fused_kernel<<<NBLK, TPB, 0, stream>>>(x, W, b, sf, out, ws);
}

// Round 8
// 189.014 us; speedup vs baseline: 2.3288x; 2.3288x over previous
//
#include <hip/hip_runtime.h>

#define C 4096
#define NROWS 16384
#define NBLK 256
#define TPB 1024
#define RPB 64                 // rows per block in phases 1/4
#define HWREG_XCC_ID 63508     // getreg imm: (size-1=31)<<11 | offset=0<<6 | id=20

typedef float f32x4 __attribute__((ext_vector_type(4)));

// ---- relaxed agent atomics (no per-op cache maintenance) ----
__device__ __forceinline__ unsigned aload(unsigned* p) {
    return __hip_atomic_load(p, __ATOMIC_RELAXED, __HIP_MEMORY_SCOPE_AGENT);
}
__device__ __forceinline__ unsigned aadd(unsigned* p, unsigned v) {
    return __hip_atomic_fetch_add(p, v, __ATOMIC_RELAXED, __HIP_MEMORY_SCOPE_AGENT);
}

// ctrl word layout (all zeroed per launch; lines padded 256 B apart):
//  [64*x] x<8 : per-XCD arrival tickets     [512] : global arrival count
//  [576]      : dummy for leader ACQ_REL    [640] : nlead   [704] : fdone
//  [1024+64*x]: per-XCD release flags
#define CTRL_WORDS 2048

// Grid barrier with ONCE-PER-XCD heavy fence (R6/R7 lesson: per-block
// release/acquire costs ~0.9 us serialized per XCD L2 -> pay it 8x, not 256x).
__device__ __forceinline__ void gbar(unsigned* ctrl, unsigned r, bool& lead,
                                     unsigned xcd) {
    __syncthreads();  // drains vmcnt: this block's stores are in its XCD L2
    if (threadIdx.x == 0) {
        unsigned tkt = aadd(&ctrl[64 * xcd], 1u);
        if (r == 1 && tkt == 0) {          // first arriver on this XCD = leader
            lead = true;
            unsigned lv = aadd(&ctrl[640], 1u);
            asm volatile("" :: "v"(lv));   // nlead-add completes before gcnt-add
        }
        aadd(&ctrl[512], 1u);
        if (lead) {
            while (aload(&ctrl[512]) < r * NBLK) __builtin_amdgcn_s_sleep(2);
            // ONE heavy fence per XCD: ACQ_REL RMW -> buffer_wbl2 + buffer_inv
            unsigned v = __hip_atomic_fetch_add(&ctrl[576], 0u, __ATOMIC_ACQ_REL,
                                                __HIP_MEMORY_SCOPE_AGENT);
            asm volatile("" :: "v"(v));    // fence completed before fdone-add
            aadd(&ctrl[704], 1u);
            unsigned nl = aload(&ctrl[640]);
            while (aload(&ctrl[704]) < r * nl) __builtin_amdgcn_s_sleep(2);
            __hip_atomic_store(&ctrl[1024 + 64 * xcd], r, __ATOMIC_RELAXED,
                               __HIP_MEMORY_SCOPE_AGENT);
        } else {
            while (aload(&ctrl[1024 + 64 * xcd]) < r) __builtin_amdgcn_s_sleep(8);
        }
    }
    __syncthreads();
}

__global__ __launch_bounds__(TPB, 4)
void fused_kernel(const float* __restrict__ x, const float* __restrict__ W,
                  const float* __restrict__ b, const int* __restrict__ sf,
                  float* __restrict__ out, float* __restrict__ ws) {
    float* part = ws;                                  // [NBLK][C] partials (4 MiB)
    float* gsum = ws + (size_t)NBLK * C;               // [C]
    unsigned* ctrl = (unsigned*)(gsum + C);            // barrier control block

    __shared__ float lds[TPB];

    const int t = threadIdx.x;                         // 0..1023
    const int bidx = blockIdx.x;                       // 0..255
    const int r0 = bidx * RPB;
    const float sf0 = (float)sf[0];
    const unsigned xcd = __builtin_amdgcn_s_getreg(HWREG_XCC_ID) & 7u;
    bool lead = false;

    // ---- Phase 1: column partials of my 64-row slice (thread t = f32x4 col t) ----
    {
        const f32x4* xv = (const f32x4*)x + (size_t)r0 * (C / 4) + t;
        f32x4 acc = {0.f, 0.f, 0.f, 0.f};
#pragma unroll 8
        for (int r = 0; r < RPB; ++r)
            acc += xv[(size_t)r * (C / 4)];
        __builtin_nontemporal_store(acc, (f32x4*)part + (size_t)bidx * (C / 4) + t);
    }
    gbar(ctrl, 1, lead, xcd);

    // ---- Phase 2: fold part[256][C] -> gsum; ALL 256 blocks, 16 cols each ----
    {
        const int col = (bidx << 4) + (t & 15);
        const int rg = t >> 4;                         // 0..63 -> rows 4*rg..4*rg+3
        float s = 0.f;
#pragma unroll
        for (int i = 0; i < 4; ++i)
            s += part[(size_t)(rg * 4 + i) * C + col];
        lds[t] = s;
        __syncthreads();
#pragma unroll
        for (int h = 32; h >= 1; h >>= 1) {
            if (rg < h) lds[t] += lds[t + h * 16];
            __syncthreads();
        }
        if (t < 16) gsum[(bidx << 4) + t] = lds[t];
    }
    gbar(ctrl, 2, lead, xcd);

    // ---- Phase 3: wave w -> row bidx*16+w: s[row]=sigmoid(sf*(W@gsum/N + b)) ----
    {
        const int wave = t >> 6, lane = t & 63;
        const int row = (bidx << 4) + wave;
        const f32x4* wv = (const f32x4*)(W + (size_t)row * C);
        const f32x4* gv = (const f32x4*)gsum;
        float acc = 0.f;
#pragma unroll
        for (int i = 0; i < 16; ++i) {
            const f32x4 w4 = __builtin_nontemporal_load(wv + (i << 6) + lane);
            const f32x4 g4 = gv[(i << 6) + lane];
            acc += w4.x * g4.x + w4.y * g4.y + w4.z * g4.z + w4.w * g4.w;
        }
#pragma unroll
        for (int off = 32; off; off >>= 1) acc += __shfl_down(acc, off);
        if (lane == 0) {
            const float y = acc * (1.0f / NROWS) + b[row];
            out[(size_t)NROWS * C + row] = 1.0f / (1.0f + __expf(-sf0 * y));
        }
    }
    gbar(ctrl, 3, lead, xcd);

    // ---- Phase 4: out = x * s over my same 64-row slice (L3-warm re-read) ----
    {
        const f32x4 sc = ((const f32x4*)(out + (size_t)NROWS * C))[t];
        const f32x4* xv = (const f32x4*)x + (size_t)r0 * (C / 4) + t;
        f32x4* ov = (f32x4*)out + (size_t)r0 * (C / 4) + t;
#pragma unroll 8
        for (int r = 0; r < RPB; ++r) {
            f32x4 v = xv[(size_t)r * (C / 4)];
            v *= sc;
            __builtin_nontemporal_store(v, ov + (size_t)r * (C / 4));
        }
    }
}

extern "C" void kernel_launch(void* const* d_in, const int* in_sizes, int n_in,
                              void* d_out, int out_size, void* d_ws, size_t ws_size,
                              hipStream_t stream) {
    const float* x = (const float*)d_in[0];   // [NROWS, C] fp32
    const float* W = (const float*)d_in[1];   // [C, C] fp32
    const float* b = (const float*)d_in[2];   // [C] fp32
    const int* sf  = (const int*)d_in[3];     // scalar int

    float* out = (float*)d_out;               // [NROWS*C] x_out ++ [C] x_scale
    float* ws  = (float*)d_ws;

    // Zero the barrier control block (8 KiB) each launch.
    const size_t ctrl_off = ((size_t)NBLK * C + C) * sizeof(float);
    hipMemsetAsync((char*)d_ws + ctrl_off, 0, CTRL_WORDS * sizeof(unsigned), stream);

    fused_kernel<<<NBLK, TPB, 0, stream>>>(x, W, b, sf, out, ws);
}

// Round 9
// 182.051 us; speedup vs baseline: 2.4179x; 1.0382x over previous
//
#include <hip/hip_runtime.h>

#define C 4096
#define NROWS 16384
#define NBLK 256
#define TPB 1024
#define RPB 64                 // rows per block in phases 1/4
#define HWREG_XCC_ID 63508     // getreg imm: (size-1=31)<<11 | offset=0<<6 | id=20

typedef float f32x4 __attribute__((ext_vector_type(4)));

__device__ __forceinline__ unsigned aload(unsigned* p) {
    return __hip_atomic_load(p, __ATOMIC_RELAXED, __HIP_MEMORY_SCOPE_AGENT);
}
__device__ __forceinline__ unsigned aadd(unsigned* p, unsigned v) {
    return __hip_atomic_fetch_add(p, v, __ATOMIC_RELAXED, __HIP_MEMORY_SCOPE_AGENT);
}

// ctrl word layout (zeroed per launch; hot lines padded 256 B apart):
//  [64*x] x<8 : per-XCD arrival counters (ONLY arrival structure — R8's global
//               counter removed: 256 same-line RMWs ~= 24.5us/barrier was the cost)
//  [576]      : dummy for leader ACQ_REL fence
//  [640]      : nlead      [704] : fence-done count
//  [1024+64*x]: per-XCD release flags
#define CTRL_WORDS 2048

// Grid barrier: relaxed per-XCD arrivals (~32 serialized RMWs/line, parallel
// across XCDs), leaders detect completion by summing the 8 counters, then ONE
// ACQ_REL RMW per XCD (wbl2+inv), leader rendezvous, per-XCD release flags.
__device__ __forceinline__ void gbar(unsigned* ctrl, unsigned r, bool& lead,
                                     unsigned xcd) {
    __syncthreads();  // drains vmcnt: this block's stores are in its XCD L2
    if (threadIdx.x == 0) {
        unsigned tkt = aadd(&ctrl[64 * xcd], 1u);
        if (r == 1 && tkt == 0) {          // first arriver on this XCD = leader
            lead = true;
            unsigned lv = aadd(&ctrl[640], 1u);
            asm volatile("" :: "v"(lv));
        }
        if (lead) {
            for (;;) {                      // wait all arrivals (sum of 8 lines)
                unsigned s = 0;
#pragma unroll
                for (int i = 0; i < 8; ++i) s += aload(&ctrl[64 * i]);
                if (s >= r * NBLK) break;
                __builtin_amdgcn_s_sleep(2);
            }
            // ONE heavy fence per XCD: ACQ_REL RMW -> buffer_wbl2 + buffer_inv
            unsigned v = __hip_atomic_fetch_add(&ctrl[576], 0u, __ATOMIC_ACQ_REL,
                                                __HIP_MEMORY_SCOPE_AGENT);
            asm volatile("" :: "v"(v));
            aadd(&ctrl[704], 1u);
            // all leaders fenced? (re-read nlead each poll: election-race guard)
            while (aload(&ctrl[704]) < r * aload(&ctrl[640]))
                __builtin_amdgcn_s_sleep(2);
            __hip_atomic_store(&ctrl[1024 + 64 * xcd], r, __ATOMIC_RELAXED,
                               __HIP_MEMORY_SCOPE_AGENT);
        } else {
            while (aload(&ctrl[1024 + 64 * xcd]) < r) __builtin_amdgcn_s_sleep(8);
        }
    }
    __syncthreads();
}

__global__ __launch_bounds__(TPB, 4)
void fused_kernel(const float* __restrict__ x, const float* __restrict__ W,
                  const float* __restrict__ b, const int* __restrict__ sf,
                  float* __restrict__ out, float* __restrict__ ws) {
    float* part = ws;                                  // [NBLK][C] partials (4 MiB)
    float* gsum = ws + (size_t)NBLK * C;               // [C]
    unsigned* ctrl = (unsigned*)(gsum + C);            // barrier control block

    __shared__ float lds[TPB];

    const int t = threadIdx.x;                         // 0..1023
    const int bidx = blockIdx.x;                       // 0..255
    const int r0 = bidx * RPB;
    const float sf0 = (float)sf[0];
    const unsigned xcd = __builtin_amdgcn_s_getreg(HWREG_XCC_ID) & 7u;
    bool lead = false;

    // ---- Phase 1: column partials of my 64-row slice (thread t = f32x4 col t) ----
    {
        const f32x4* xv = (const f32x4*)x + (size_t)r0 * (C / 4) + t;
        f32x4 acc = {0.f, 0.f, 0.f, 0.f};
#pragma unroll 8
        for (int r = 0; r < RPB; ++r)
            acc += xv[(size_t)r * (C / 4)];
        __builtin_nontemporal_store(acc, (f32x4*)part + (size_t)bidx * (C / 4) + t);
    }
    gbar(ctrl, 1, lead, xcd);

    // ---- Phase 2: fold part[256][C] -> gsum; ALL 256 blocks, 16 cols each ----
    {
        const int col = (bidx << 4) + (t & 15);
        const int rg = t >> 4;                         // 0..63 -> rows 4*rg..4*rg+3
        float s = 0.f;
#pragma unroll
        for (int i = 0; i < 4; ++i)
            s += part[(size_t)(rg * 4 + i) * C + col];
        lds[t] = s;
        __syncthreads();
#pragma unroll
        for (int h = 32; h >= 1; h >>= 1) {
            if (rg < h) lds[t] += lds[t + h * 16];
            __syncthreads();
        }
        if (t < 16) gsum[(bidx << 4) + t] = lds[t];
    }
    gbar(ctrl, 2, lead, xcd);

    // ---- Phase 3: wave w -> row bidx*16+w: s[row]=sigmoid(sf*(W@gsum/N + b)) ----
    {
        const int wave = t >> 6, lane = t & 63;
        const int row = (bidx << 4) + wave;
        const f32x4* wv = (const f32x4*)(W + (size_t)row * C);
        const f32x4* gv = (const f32x4*)gsum;
        float acc = 0.f;
#pragma unroll
        for (int i = 0; i < 16; ++i) {
            const f32x4 w4 = __builtin_nontemporal_load(wv + (i << 6) + lane);
            const f32x4 g4 = gv[(i << 6) + lane];
            acc += w4.x * g4.x + w4.y * g4.y + w4.z * g4.z + w4.w * g4.w;
        }
#pragma unroll
        for (int off = 32; off; off >>= 1) acc += __shfl_down(acc, off);
        if (lane == 0) {
            const float y = acc * (1.0f / NROWS) + b[row];
            out[(size_t)NROWS * C + row] = 1.0f / (1.0f + __expf(-sf0 * y));
        }
    }
    gbar(ctrl, 3, lead, xcd);

    // ---- Phase 4: out = x * s over my same 64-row slice (L3-warm re-read) ----
    {
        const f32x4 sc = ((const f32x4*)(out + (size_t)NROWS * C))[t];
        const f32x4* xv = (const f32x4*)x + (size_t)r0 * (C / 4) + t;
        f32x4* ov = (f32x4*)out + (size_t)r0 * (C / 4) + t;
#pragma unroll 8
        for (int r = 0; r < RPB; ++r) {
            f32x4 v = xv[(size_t)r * (C / 4)];
            v *= sc;
            __builtin_nontemporal_store(v, ov + (size_t)r * (C / 4));
        }
    }
}

extern "C" void kernel_launch(void* const* d_in, const int* in_sizes, int n_in,
                              void* d_out, int out_size, void* d_ws, size_t ws_size,
                              hipStream_t stream) {
    const float* x = (const float*)d_in[0];   // [NROWS, C] fp32
    const float* W = (const float*)d_in[1];   // [C, C] fp32
    const float* b = (const float*)d_in[2];   // [C] fp32
    const int* sf  = (const int*)d_in[3];     // scalar int

    float* out = (float*)d_out;               // [NROWS*C] x_out ++ [C] x_scale
    float* ws  = (float*)d_ws;

    // Zero the barrier control block (8 KiB) each launch.
    const size_t ctrl_off = ((size_t)NBLK * C + C) * sizeof(float);
    hipMemsetAsync((char*)d_ws + ctrl_off, 0, CTRL_WORDS * sizeof(unsigned), stream);

    fused_kernel<<<NBLK, TPB, 0, stream>>>(x, W, b, sf, out, ws);
}

// Round 10
// 180.691 us; speedup vs baseline: 2.4361x; 1.0075x over previous
//
#include <hip/hip_runtime.h>

#define C 4096
#define NROWS 16384
#define NBLK 256
#define TPB 1024
#define RPB 64                 // rows per block in phases 1/4
#define HWREG_XCC_ID 63508     // getreg imm: (size-1=31)<<11 | offset=0<<6 | id=20

typedef float f32x4 __attribute__((ext_vector_type(4)));

__device__ __forceinline__ unsigned aload(unsigned* p) {
    return __hip_atomic_load(p, __ATOMIC_RELAXED, __HIP_MEMORY_SCOPE_AGENT);
}
__device__ __forceinline__ unsigned aadd(unsigned* p, unsigned v) {
    return __hip_atomic_fetch_add(p, v, __ATOMIC_RELAXED, __HIP_MEMORY_SCOPE_AGENT);
}

// ctrl layout (u32 words; hot lines 256 B apart; all zeroed per launch):
//  [64*x]  x<8 : arrival counters      [512+64*x] x<8 : election counters
//  [1024]      : fence dummy           [1088] : nlead   [1152] : fence-done
//  [1280+64*x] : per-XCD release flags
#define CTRL_WORDS 2048

// Grid barrier: relaxed per-XCD arrivals; once-per-XCD ACQ_REL fence
// (wbl2+inv); leader rendezvous; per-XCD release flags.
// R10 fix vs R9: leadership via a SEPARATE election counter, and nlead++
// completes (return consumed) BEFORE the arrival add — closes the window
// where a leader could read a stale nlead after seeing all arrivals.
__device__ __forceinline__ void gbar(unsigned* ctrl, unsigned r, bool& lead,
                                     unsigned xcd) {
    __syncthreads();  // drains vmcnt: this block's mem ops are issued/complete
    if (threadIdx.x == 0) {
        if (r == 1) {
            if (aadd(&ctrl[512 + 64 * xcd], 1u) == 0) {   // first block on XCD
                lead = true;
                unsigned lv = aadd(&ctrl[1088], 1u);       // nlead++
                asm volatile("" :: "v"(lv) : "memory");    // complete before arrival
            }
        }
        aadd(&ctrl[64 * xcd], 1u);                         // arrival
        if (lead) {
            for (;;) {                                     // all 256 arrived?
                unsigned s = 0;
#pragma unroll
                for (int i = 0; i < 8; ++i) s += aload(&ctrl[64 * i]);
                if (s >= r * NBLK) break;
                __builtin_amdgcn_s_sleep(2);
            }
            // ONE heavy fence per XCD: ACQ_REL RMW -> buffer_wbl2 + buffer_inv
            unsigned v = __hip_atomic_fetch_add(&ctrl[1024], 0u, __ATOMIC_ACQ_REL,
                                                __HIP_MEMORY_SCOPE_AGENT);
            asm volatile("" :: "v"(v) : "memory");
            aadd(&ctrl[1152], 1u);                         // fence-done++
            while (aload(&ctrl[1152]) < r * aload(&ctrl[1088]))
                __builtin_amdgcn_s_sleep(2);
            __hip_atomic_store(&ctrl[1280 + 64 * xcd], r, __ATOMIC_RELAXED,
                               __HIP_MEMORY_SCOPE_AGENT);
        } else {
            while (aload(&ctrl[1280 + 64 * xcd]) < r) __builtin_amdgcn_s_sleep(8);
        }
    }
    __syncthreads();
}

__global__ __launch_bounds__(TPB, 4)
void fused_kernel(const float* __restrict__ x, const float* __restrict__ W,
                  const float* __restrict__ b, const int* __restrict__ sf,
                  float* __restrict__ out, float* __restrict__ ws) {
    float* gsumX = ws;                                 // [8][C] per-XCD col sums
    unsigned* ctrl = (unsigned*)(ws + 8 * (size_t)C);  // barrier control block

    __shared__ float g_lds[C];                         // summed gsum (16 KB)

    const int t = threadIdx.x;                         // 0..1023
    const int bidx = blockIdx.x;                       // 0..255
    const int r0 = bidx * RPB;
    const float sf0 = (float)sf[0];
    const unsigned xcd = __builtin_amdgcn_s_getreg(HWREG_XCC_ID) & 7u;
    bool lead = false;

    // ---- Phase 1: col sums of my 64-row slice -> per-XCD atomic gsum copy ----
    // No partial buffer, no fold phase, no dirty L2 at the fence.
    {
        const f32x4* xv = (const f32x4*)x + (size_t)r0 * (C / 4) + t;
        f32x4 acc = {0.f, 0.f, 0.f, 0.f};
#pragma unroll 8
        for (int r = 0; r < RPB; ++r)
            acc += xv[(size_t)r * (C / 4)];
        float* g = gsumX + (size_t)xcd * C + t * 4;
        atomicAdd(g + 0, acc.x);
        atomicAdd(g + 1, acc.y);
        atomicAdd(g + 2, acc.z);
        atomicAdd(g + 3, acc.w);
    }
    gbar(ctrl, 1, lead, xcd);

    // ---- Phase 2: sum the 8 copies into LDS, then wave w -> row bidx*16+w ----
    {
        f32x4 s = {0.f, 0.f, 0.f, 0.f};
#pragma unroll
        for (int xx = 0; xx < 8; ++xx)
            s += ((const f32x4*)(gsumX + (size_t)xx * C))[t];
        ((f32x4*)g_lds)[t] = s;
    }
    __syncthreads();
    {
        const int wave = t >> 6, lane = t & 63;
        const int row = (bidx << 4) + wave;
        const f32x4* wv = (const f32x4*)(W + (size_t)row * C);
        const f32x4* gv = (const f32x4*)g_lds;
        float acc = 0.f;
#pragma unroll
        for (int i = 0; i < 16; ++i) {
            const f32x4 w4 = __builtin_nontemporal_load(wv + (i << 6) + lane);
            const f32x4 g4 = gv[(i << 6) + lane];
            acc += w4.x * g4.x + w4.y * g4.y + w4.z * g4.z + w4.w * g4.w;
        }
#pragma unroll
        for (int off = 32; off; off >>= 1) acc += __shfl_down(acc, off);
        if (lane == 0) {
            const float y = acc * (1.0f / NROWS) + b[row];
            out[(size_t)NROWS * C + row] = 1.0f / (1.0f + __expf(-sf0 * y));
        }
    }
    gbar(ctrl, 2, lead, xcd);

    // ---- Phase 3: out = x * s over my same 64-row slice (L3-warm re-read) ----
    {
        const f32x4 sc = ((const f32x4*)(out + (size_t)NROWS * C))[t];
        const f32x4* xv = (const f32x4*)x + (size_t)r0 * (C / 4) + t;
        f32x4* ov = (f32x4*)out + (size_t)r0 * (C / 4) + t;
#pragma unroll 8
        for (int r = 0; r < RPB; ++r) {
            f32x4 v = xv[(size_t)r * (C / 4)];
            v *= sc;
            __builtin_nontemporal_store(v, ov + (size_t)r * (C / 4));
        }
    }
}

extern "C" void kernel_launch(void* const* d_in, const int* in_sizes, int n_in,
                              void* d_out, int out_size, void* d_ws, size_t ws_size,
                              hipStream_t stream) {
    const float* x = (const float*)d_in[0];   // [NROWS, C] fp32
    const float* W = (const float*)d_in[1];   // [C, C] fp32
    const float* b = (const float*)d_in[2];   // [C] fp32
    const int* sf  = (const int*)d_in[3];     // scalar int

    float* out = (float*)d_out;               // [NROWS*C] x_out ++ [C] x_scale
    float* ws  = (float*)d_ws;

    // Zero gsumX (atomic accumulators) + ctrl in one async memset (136 KB).
    hipMemsetAsync(d_ws, 0, (8 * (size_t)C) * sizeof(float)
                            + CTRL_WORDS * sizeof(unsigned), stream);

    fused_kernel<<<NBLK, TPB, 0, stream>>>(x, W, b, sf, out, ws);
}

// Round 11
// 165.635 us; speedup vs baseline: 2.6576x; 1.0909x over previous
//
#include <hip/hip_runtime.h>

#define C 4096
#define NROWS 16384
#define NBLK 512               // K3 grid: 2 blocks/CU, 32 waves/CU
#define HWREG_XCC_ID 63508     // getreg imm: (size-1=31)<<11 | offset=0<<6 | id=20
#define PARTS 256
#define CTRL_WORDS 2048

typedef float f32x4 __attribute__((ext_vector_type(4)));

__device__ __forceinline__ unsigned aload(unsigned* p) {
    return __hip_atomic_load(p, __ATOMIC_RELAXED, __HIP_MEMORY_SCOPE_AGENT);
}
__device__ __forceinline__ unsigned aadd(unsigned* p, unsigned v) {
    return __hip_atomic_fetch_add(p, v, __ATOMIC_RELAXED, __HIP_MEMORY_SCOPE_AGENT);
}

// R10-validated grid barrier: relaxed per-XCD arrivals, once-per-XCD ACQ_REL
// fence (wbl2+inv), leader rendezvous, per-XCD release flags. Single round.
__device__ __forceinline__ void gbar(unsigned* ctrl, unsigned xcd) {
    bool lead = false;
    __syncthreads();
    if (threadIdx.x == 0) {
        if (aadd(&ctrl[512 + 64 * xcd], 1u) == 0) {        // leader election
            lead = true;
            unsigned lv = aadd(&ctrl[1088], 1u);            // nlead++
            asm volatile("" :: "v"(lv) : "memory");
        }
        aadd(&ctrl[64 * xcd], 1u);                          // arrival
        if (lead) {
            for (;;) {
                unsigned s = 0;
#pragma unroll
                for (int i = 0; i < 8; ++i) s += aload(&ctrl[64 * i]);
                if (s >= NBLK) break;
                __builtin_amdgcn_s_sleep(2);
            }
            unsigned v = __hip_atomic_fetch_add(&ctrl[1024], 0u, __ATOMIC_ACQ_REL,
                                                __HIP_MEMORY_SCOPE_AGENT);
            asm volatile("" :: "v"(v) : "memory");
            aadd(&ctrl[1152], 1u);
            while (aload(&ctrl[1152]) < aload(&ctrl[1088]))
                __builtin_amdgcn_s_sleep(2);
            __hip_atomic_store(&ctrl[1280 + 64 * xcd], 1u, __ATOMIC_RELAXED,
                               __HIP_MEMORY_SCOPE_AGENT);
        } else {
            while (aload(&ctrl[1280 + 64 * xcd]) < 1u) __builtin_amdgcn_s_sleep(8);
        }
    }
    __syncthreads();
}

// ---- K1: column partials (R2's proven 43us shape); nt stores for partials ----
__global__ void colsum_partial(const float* __restrict__ x, float* __restrict__ part) {
    const int c4 = blockIdx.x * blockDim.x + threadIdx.x;   // 0..1023
    const int r0 = blockIdx.y * (NROWS / PARTS);
    const f32x4* xv = (const f32x4*)x;
    f32x4 acc = {0.f, 0.f, 0.f, 0.f};
#pragma unroll 4
    for (int r = 0; r < NROWS / PARTS; ++r)
        acc += xv[(size_t)(r0 + r) * (C / 4) + c4];
    __builtin_nontemporal_store(acc, (f32x4*)part + (size_t)blockIdx.y * (C / 4) + c4);
}

// ---- K2: fold PARTS partial rows -> gsum ----
__global__ void colsum_reduce(const float* __restrict__ part, float* __restrict__ gsum) {
    const int c = blockIdx.x * blockDim.x + threadIdx.x;
    float s = 0.f;
#pragma unroll 8
    for (int r = 0; r < PARTS; ++r) s += part[(size_t)r * C + c];
    gsum[c] = s;
}

// ---- K3: matvec (nt W) + ONE grid barrier + scale (x from L3, nt out) ----
__global__ __launch_bounds__(512, 8)   // 8 waves/EU -> 2 blocks/CU, 32 waves/CU
void matvec_scale(const float* __restrict__ x, const float* __restrict__ W,
                  const float* __restrict__ b, const int* __restrict__ sf,
                  const float* __restrict__ gsum, float* __restrict__ out,
                  unsigned* __restrict__ ctrl) {
    __shared__ float g_lds[C];

    const int t = threadIdx.x;                  // 0..511
    const int bidx = blockIdx.x;                // 0..511
    const float sf0 = (float)sf[0];
    const unsigned xcd = __builtin_amdgcn_s_getreg(HWREG_XCC_ID) & 7u;

    // stage gsum in LDS
    ((f32x4*)g_lds)[t]       = ((const f32x4*)gsum)[t];
    ((f32x4*)g_lds)[t + 512] = ((const f32x4*)gsum)[t + 512];
    __syncthreads();

    // matvec: wave w -> row bidx*8 + w
    {
        const int wave = t >> 6, lane = t & 63;
        const int row = (bidx << 3) + wave;
        const f32x4* wv = (const f32x4*)(W + (size_t)row * C);
        const f32x4* gv = (const f32x4*)g_lds;
        float acc = 0.f;
#pragma unroll
        for (int i = 0; i < 16; ++i) {
            const f32x4 w4 = __builtin_nontemporal_load(wv + (i << 6) + lane);
            const f32x4 g4 = gv[(i << 6) + lane];
            acc += w4.x * g4.x + w4.y * g4.y + w4.z * g4.z + w4.w * g4.w;
        }
#pragma unroll
        for (int off = 32; off; off >>= 1) acc += __shfl_down(acc, off);
        if (lane == 0) {
            const float y = acc * (1.0f / NROWS) + b[row];
            out[(size_t)NROWS * C + row] = 1.0f / (1.0f + __expf(-sf0 * y));
        }
    }

    gbar(ctrl, xcd);   // the ONLY grid barrier

    // scale: rows bidx*32 .. +31; thread t owns f32x4 cols t and t+512
    {
        const f32x4* sv = (const f32x4*)(out + (size_t)NROWS * C);
        const f32x4 sc0 = sv[t], sc1 = sv[t + 512];
        const int r0 = bidx << 5;
        const f32x4* xv = (const f32x4*)x + (size_t)r0 * (C / 4);
        f32x4* ov = (f32x4*)out + (size_t)r0 * (C / 4);
#pragma unroll 4
        for (int r = 0; r < 32; ++r) {
            f32x4 v0 = xv[(size_t)r * (C / 4) + t];
            f32x4 v1 = xv[(size_t)r * (C / 4) + t + 512];
            v0 *= sc0;
            v1 *= sc1;
            __builtin_nontemporal_store(v0, ov + (size_t)r * (C / 4) + t);
            __builtin_nontemporal_store(v1, ov + (size_t)r * (C / 4) + t + 512);
        }
    }
}

extern "C" void kernel_launch(void* const* d_in, const int* in_sizes, int n_in,
                              void* d_out, int out_size, void* d_ws, size_t ws_size,
                              hipStream_t stream) {
    const float* x = (const float*)d_in[0];   // [NROWS, C] fp32
    const float* W = (const float*)d_in[1];   // [C, C] fp32
    const float* b = (const float*)d_in[2];   // [C] fp32
    const int* sf  = (const int*)d_in[3];     // scalar int

    float* out = (float*)d_out;               // [NROWS*C] x_out ++ [C] x_scale
    float* part = (float*)d_ws;               // [PARTS][C] partials (4 MiB)
    float* gsum = part + (size_t)PARTS * C;   // [C]
    unsigned* ctrl = (unsigned*)(gsum + C);   // barrier control (8 KiB, zeroed)

    hipMemsetAsync(ctrl, 0, CTRL_WORDS * sizeof(unsigned), stream);

    colsum_partial<<<dim3(4, PARTS), 256, 0, stream>>>(x, part);
    colsum_reduce<<<C / 256, 256, 0, stream>>>(part, gsum);
    matvec_scale<<<NBLK, 512, 0, stream>>>(x, W, b, sf, gsum, out, ctrl);
}